// Round 8
// baseline (169.495 us; speedup 1.0000x reference)
//
#include <hip/hip_runtime.h>
#include <hip/hip_bf16.h>
#include <cstdint>
#include <cmath>

typedef __bf16 bf16_t;
typedef __bf16 bf16x8 __attribute__((ext_vector_type(8)));
typedef __bf16 bf16x4 __attribute__((ext_vector_type(4)));
typedef float  f32x4  __attribute__((ext_vector_type(4)));

#define MFMA16(a, b, c) __builtin_amdgcn_mfma_f32_16x16x32_bf16(a, b, c, 0, 0, 0)

constexpr int   SS    = 2048;
constexpr int   DD    = 1024;
constexpr int   HH    = 16;
constexpr float SCALE = 0.125f;          // 1/sqrt(64)
constexpr float L2E   = 1.44269504088896f;

// ---------------------------------------------------------------------------
// Runtime input-dtype detector (bf16 weights vs fp32 read as uint16 halves).
__device__ __forceinline__ bool detect_fp32(const uint16_t* w) {
    uint16_t v = w[threadIdx.x & 63];
    int e = (v >> 7) & 0xFF;
    unsigned long long m = __ballot(e >= 0x80);
    return __popcll(m) >= 4;
}

__device__ __forceinline__ float ldin(const void* p, size_t i, bool f32) {
    return f32 ? ((const float*)p)[i] : (float)((const bf16_t*)p)[i];
}

// ---------------------------------------------------------------------------
// async global->LDS, 16B per lane. LDS dst must be wave-uniform base + lane*16.
__device__ __forceinline__ void gload_lds16(const bf16_t* g, bf16_t* l) {
    __builtin_amdgcn_global_load_lds(
        (const __attribute__((address_space(1))) void*)(g),
        (__attribute__((address_space(3))) void*)(l), 16, 0, 0);
}

// ---------------------------------------------------------------------------
// Merged prep: blocks [0,1024) do 8-wide vectorized RoPE+cast;
// blocks [1024,5120) transpose the four 1024x1024 weights to bf16 [n][k].
// hiddenb is only materialized on the fp32 path (bf16 path reads hidden raw).
__global__ __launch_bounds__(256) void prep_kernel(
    const void* __restrict__ hidden, const void* __restrict__ Wq,
    const void* __restrict__ Wk, const void* __restrict__ Wv,
    const void* __restrict__ Wo,
    bf16_t* __restrict__ roped, bf16_t* __restrict__ hiddenb,
    bf16_t* __restrict__ WqT, bf16_t* __restrict__ WkT,
    bf16_t* __restrict__ WvT, bf16_t* __restrict__ WoT) {
    const bool f32 = detect_fp32((const uint16_t*)Wq);
    __shared__ bf16_t tile[32][33];
    if (blockIdx.x < 1024) {
        int gid = blockIdx.x * 256 + threadIdx.x;   // 2^18 threads
        int ic = (gid & 3) * 8;                     // i base within [0,32)
        int h  = (gid >> 2) & 15;
        int s  = (gid >> 6) & 2047;
        int b  = gid >> 17;
        size_t base = ((size_t)(b * SS + s)) * DD + h * 64 + ic;
        float x[8], y[8];
        if (f32) {
            const float* hp = (const float*)hidden;
            f32x4 x0 = *(const f32x4*)(hp + base);
            f32x4 x1 = *(const f32x4*)(hp + base + 4);
            f32x4 y0 = *(const f32x4*)(hp + base + 32);
            f32x4 y1 = *(const f32x4*)(hp + base + 36);
#pragma unroll
            for (int j = 0; j < 4; ++j) {
                x[j] = x0[j]; x[4 + j] = x1[j];
                y[j] = y0[j]; y[4 + j] = y1[j];
            }
        } else {
            const bf16_t* hp = (const bf16_t*)hidden;
            bf16x8 xv = *(const bf16x8*)(hp + base);
            bf16x8 yv = *(const bf16x8*)(hp + base + 32);
#pragma unroll
            for (int j = 0; j < 8; ++j) { x[j] = (float)xv[j]; y[j] = (float)yv[j]; }
        }
        bf16x8 ro, rh;
#pragma unroll
        for (int j = 0; j < 8; ++j) {
            int i = ic + j;
            float invf = exp2f(-(float)i * (13.287712379549449f / 32.0f));
            float sn, cs;
            __sincosf((float)s * invf, &sn, &cs);
            ro[j]  = (bf16_t)(x[j] * cs - y[j] * sn);
            rh[j]  = (bf16_t)(y[j] * cs + x[j] * sn);
        }
        *(bf16x8*)(roped + base)      = ro;
        *(bf16x8*)(roped + base + 32) = rh;
        if (f32) {
            bf16x8 hb0, hb1;
#pragma unroll
            for (int j = 0; j < 8; ++j) { hb0[j] = (bf16_t)x[j]; hb1[j] = (bf16_t)y[j]; }
            *(bf16x8*)(hiddenb + base)      = hb0;
            *(bf16x8*)(hiddenb + base + 32) = hb1;
        }
    } else {
        int w = blockIdx.x - 1024;            // 0..4095
        int z = w >> 10;
        int yy = (w >> 5) & 31, xx = w & 31;
        const void* src = (z == 0) ? Wq : (z == 1) ? Wk : (z == 2) ? Wv : Wo;
        bf16_t*     dst = (z == 0) ? WqT : (z == 1) ? WkT : (z == 2) ? WvT : WoT;
        int tx = threadIdx.x & 31, ty = threadIdx.x >> 5;   // 32 x 8
        int x0 = xx * 32, y0 = yy * 32;
#pragma unroll
        for (int j = 0; j < 4; ++j)
            tile[ty + j * 8][tx] =
                (bf16_t)ldin(src, (size_t)(y0 + ty + j * 8) * DD + x0 + tx, f32);
        __syncthreads();
#pragma unroll
        for (int j = 0; j < 4; ++j)
            dst[(size_t)(x0 + ty + j * 8) * DD + y0 + tx] = tile[tx][ty + j * 8];
    }
}

// ---------------------------------------------------------------------------
// Staging helpers, BK=64.
// 128 rows x 64 cols tile = 1024 chunks of 16B; 4 chunks/thread.
__device__ __forceinline__ void stage_128x64(const bf16_t* A, int m0, int k0,
                                             bf16_t* As, int tid) {
#pragma unroll
    for (int i = 0; i < 4; ++i) {
        int c = tid + i * 256;
        gload_lds16(A + (size_t)(m0 + (c >> 3)) * DD + k0 + (c & 7) * 8, As + c * 8);
    }
}
// 64 rows x 64 cols tile = 512 chunks; 2 chunks/thread.
__device__ __forceinline__ void stage_64x64(const bf16_t* Bt, int n0, int k0,
                                            bf16_t* Bs, int tid) {
#pragma unroll
    for (int i = 0; i < 2; ++i) {
        int c = tid + i * 256;
        gload_lds16(Bt + (size_t)(n0 + (c >> 3)) * DD + k0 + (c & 7) * 8, Bs + c * 8);
    }
}

// ---------------------------------------------------------------------------
// Fused QKV GEMM, 128x128 tiles, BK=64. Grid: 512 linear blocks.
//   z=0 (256 blocks): Q and K 128x128 tiles fused (shared A=roped in LDS).
//   z=1 (256 blocks): V 128x128 tile -> transposed (b,h,d,s) output.
// 4 waves in 2x2; each wave owns 64x64 = 4x4 frags per output.
// XCD-slab swizzle: xcd = lin&7 owns mb in [xcd*4, xcd*4+4) x all nb
// (A-slab 1 MB + B 2 MB < 4 MB per-XCD L2).
__global__ __launch_bounds__(256, 2) void gemm_qkv_fused(
    const bf16_t* __restrict__ roped, const void* __restrict__ hidden_raw,
    const bf16_t* __restrict__ hiddenb, const uint16_t* __restrict__ wdet,
    const bf16_t* __restrict__ WqT, const bf16_t* __restrict__ WkT,
    const bf16_t* __restrict__ WvT,
    bf16_t* __restrict__ Qo, bf16_t* __restrict__ Ko, bf16_t* __restrict__ Vt) {
    __shared__ __align__(16) bf16_t As[128 * 64];
    __shared__ __align__(16) bf16_t B1[128 * 64];
    __shared__ __align__(16) bf16_t B2[128 * 64];
    const int tid = threadIdx.x, lane = tid & 63, quad = lane >> 4, l16 = lane & 15;
    const int wave = tid >> 6, wm = (wave >> 1) * 64, wn = (wave & 1) * 64;

    const int lin = blockIdx.x;
    const int z   = lin >> 8;               // 0: QK, 1: V
    const int r   = lin & 255;
    const int xcd = r & 7, rem = r >> 3;    // rem: 0..31
    const int mb  = xcd * 4 + (rem & 3);    // 0..31
    const int nb  = rem >> 2;               // 0..7
    const int m0  = mb * 128, n0 = nb * 128;

    if (z == 0) {
        f32x4 acc1[4][4], acc2[4][4];
#pragma unroll
        for (int i = 0; i < 4; ++i)
#pragma unroll
            for (int j = 0; j < 4; ++j) { acc1[i][j] = (f32x4)0.0f; acc2[i][j] = (f32x4)0.0f; }

        for (int k0 = 0; k0 < DD; k0 += 64) {
            stage_128x64(roped, m0, k0, As, tid);
            stage_128x64(WqT, n0, k0, B1, tid);
            stage_128x64(WkT, n0, k0, B2, tid);
            __syncthreads();
#pragma unroll
            for (int half = 0; half < 2; ++half) {
                bf16x8 af[4], b1f[4], b2f[4];
#pragma unroll
                for (int t = 0; t < 4; ++t) {
                    af[t]  = *(const bf16x8*)(As + (wm + t * 16 + l16) * 64 + half * 32 + quad * 8);
                    b1f[t] = *(const bf16x8*)(B1 + (wn + t * 16 + l16) * 64 + half * 32 + quad * 8);
                    b2f[t] = *(const bf16x8*)(B2 + (wn + t * 16 + l16) * 64 + half * 32 + quad * 8);
                }
#pragma unroll
                for (int i = 0; i < 4; ++i)
#pragma unroll
                    for (int j = 0; j < 4; ++j) {
                        acc1[i][j] = MFMA16(af[i], b1f[j], acc1[i][j]);
                        acc2[i][j] = MFMA16(af[i], b2f[j], acc2[i][j]);
                    }
            }
            __syncthreads();
        }
        // epilogue: Q,K -> (b,h,s,d); n spans 2 heads
#pragma unroll
        for (int i = 0; i < 4; ++i) {
            int mbase = m0 + wm + i * 16 + quad * 4;
            int b = mbase >> 11, sl = mbase & 2047;
#pragma unroll
            for (int j = 0; j < 4; ++j) {
                int n = n0 + wn + j * 16 + l16;
                int h = n >> 6, d = n & 63;
                size_t base = (((size_t)b * HH + h) * SS + sl) * 64 + d;
#pragma unroll
                for (int rr = 0; rr < 4; ++rr) {
                    Qo[base + 64 * rr] = (bf16_t)acc1[i][j][rr];
                    Ko[base + 64 * rr] = (bf16_t)acc2[i][j][rr];
                }
            }
        }
    } else {
        const bool f32 = detect_fp32(wdet);
        const bf16_t* A = f32 ? hiddenb : (const bf16_t*)hidden_raw;
        f32x4 acc[4][4];
#pragma unroll
        for (int i = 0; i < 4; ++i)
#pragma unroll
            for (int j = 0; j < 4; ++j) acc[i][j] = (f32x4)0.0f;

        for (int k0 = 0; k0 < DD; k0 += 64) {
            stage_128x64(A, m0, k0, As, tid);
            stage_128x64(WvT, n0, k0, B1, tid);
            __syncthreads();
#pragma unroll
            for (int half = 0; half < 2; ++half) {
                bf16x8 af[4], b1f[4];
#pragma unroll
                for (int t = 0; t < 4; ++t) {
                    af[t]  = *(const bf16x8*)(As + (wm + t * 16 + l16) * 64 + half * 32 + quad * 8);
                    b1f[t] = *(const bf16x8*)(B1 + (wn + t * 16 + l16) * 64 + half * 32 + quad * 8);
                }
#pragma unroll
                for (int i = 0; i < 4; ++i)
#pragma unroll
                    for (int j = 0; j < 4; ++j)
                        acc[i][j] = MFMA16(af[i], b1f[j], acc[i][j]);
            }
            __syncthreads();
        }
        // epilogue: V -> transposed (b,h,d,s), 4 consecutive s per bf16x4 store
#pragma unroll
        for (int i = 0; i < 4; ++i) {
            int mbase = m0 + wm + i * 16 + quad * 4;
            int b = mbase >> 11, sl = mbase & 2047;
#pragma unroll
            for (int j = 0; j < 4; ++j) {
                int n = n0 + wn + j * 16 + l16;
                int h = n >> 6, d = n & 63;
                bf16x4 v;
                v[0] = (bf16_t)acc[i][j][0]; v[1] = (bf16_t)acc[i][j][1];
                v[2] = (bf16_t)acc[i][j][2]; v[3] = (bf16_t)acc[i][j][3];
                *(bf16x4*)(Vt + (((size_t)b * HH + h) * 64 + d) * SS + sl) = v;
            }
        }
    }
}

// ---------------------------------------------------------------------------
// Banded flash attention: 4-wave blocks (64 queries), 32-key tiles staged to
// LDS with prefetch-ahead double buffer (barrier -> issue next stage -> compute).
__global__ __launch_bounds__(256) void attn_kernel(
    const bf16_t* __restrict__ Q, const bf16_t* __restrict__ Kk,
    const bf16_t* __restrict__ Vt, bf16_t* __restrict__ attn) {
    __shared__ __align__(16) bf16_t Ks[2][32 * 64];   // 4 KB each
    __shared__ __align__(16) bf16_t Vs[2][64 * 32];   // Vt tile [d][k], 4 KB each
    __shared__ __align__(16) bf16_t Pl[4][16 * 40];   // per-wave P, pitch 40
    const int tid = threadIdx.x, wave = tid >> 6, lane = tid & 63;
    const int quad = lane >> 4, l16 = lane & 15;

    int lin = (blockIdx.x >> 3) + 128 * (blockIdx.x & 7);   // XCD swizzle
    const int qb0 = (lin & 31) * 64;
    const int h   = (lin >> 5) & 15;
    const int b   = lin >> 9;
    const int qw  = qb0 + wave * 16;

    const size_t bh = (size_t)b * HH + h;
    const bf16_t* Qp = Q  + bh * SS * 64;
    const bf16_t* Kp = Kk + bh * SS * 64;
    const bf16_t* Vp = Vt + bh * 64 * SS;
    bf16_t* P = &Pl[wave][0];

    bf16x8 q0 = *(const bf16x8*)(Qp + (size_t)(qw + l16) * 64 + quad * 8);
    bf16x8 q1 = *(const bf16x8*)(Qp + (size_t)(qw + l16) * 64 + 32 + quad * 8);

    f32x4 Oacc[4];
#pragma unroll
    for (int t = 0; t < 4; ++t) Oacc[t] = (f32x4)0.0f;
    float lsum[4] = {0.f, 0.f, 0.f, 0.f};

    int lo = qb0 - 127; if (lo < 0) lo = 0; lo &= ~31;
    int hi = qb0 + 63 + 127; if (hi > SS - 1) hi = SS - 1;

    const int krow = tid >> 3, kcol = (tid & 7) * 8;   // K tile 32x64
    const int vrow = tid >> 2, vcol = (tid & 3) * 8;   // V^T tile 64x32

    gload_lds16(Kp + (size_t)(lo + krow) * 64 + kcol, &Ks[0][0] + tid * 8);
    gload_lds16(Vp + (size_t)vrow * SS + lo + vcol, &Vs[0][0] + tid * 8);

    int parity = 0;
    for (int kt = lo; kt <= hi; kt += 32, parity ^= 1) {
        __syncthreads();   // drains vmcnt -> buf[parity] ready; fences frag reads

        if (kt + 32 <= hi) {   // prefetch next tile into the other buffer
            gload_lds16(Kp + (size_t)(kt + 32 + krow) * 64 + kcol,
                        &Ks[parity ^ 1][0] + tid * 8);
            gload_lds16(Vp + (size_t)vrow * SS + (kt + 32) + vcol,
                        &Vs[parity ^ 1][0] + tid * 8);
        }

        const bf16_t* Kl = &Ks[parity][0];
        const bf16_t* Vl = &Vs[parity][0];
        bf16x8 k00 = *(const bf16x8*)(Kl + l16 * 64 + quad * 8);
        bf16x8 k01 = *(const bf16x8*)(Kl + l16 * 64 + 32 + quad * 8);
        bf16x8 k10 = *(const bf16x8*)(Kl + (16 + l16) * 64 + quad * 8);
        bf16x8 k11 = *(const bf16x8*)(Kl + (16 + l16) * 64 + 32 + quad * 8);
        bf16x8 vf[4];
#pragma unroll
        for (int t = 0; t < 4; ++t)
            vf[t] = *(const bf16x8*)(Vl + (t * 16 + l16) * 32 + quad * 8);

        f32x4 s0 = MFMA16(q0, k00, (f32x4)0.0f);  s0 = MFMA16(q1, k01, s0);
        f32x4 s1 = MFMA16(q0, k10, (f32x4)0.0f);  s1 = MFMA16(q1, k11, s1);

        const int kr0 = kt + l16, kr1 = kt + 16 + l16;
#pragma unroll
        for (int r = 0; r < 4; ++r) {
            int qa = qw + quad * 4 + r;
            int d0 = qa - kr0; if (d0 < 0) d0 = -d0;
            int d1 = qa - kr1; if (d1 < 0) d1 = -d1;
            float p0 = (d0 < 128) ? exp2f(s0[r] * (SCALE * L2E)) : 0.0f;
            float p1 = (d1 < 128) ? exp2f(s1[r] * (SCALE * L2E)) : 0.0f;
            lsum[r] += p0 + p1;
            P[(quad * 4 + r) * 40 + l16]      = (bf16_t)p0;
            P[(quad * 4 + r) * 40 + 16 + l16] = (bf16_t)p1;
        }
        // per-wave DS ordering: write -> wait -> read (P is wave-private)
        __asm__ volatile("s_waitcnt lgkmcnt(0)" ::: "memory");
        bf16x8 pf = *(const bf16x8*)(P + l16 * 40 + quad * 8);  // A-layout P
#pragma unroll
        for (int t = 0; t < 4; ++t)
            Oacc[t] = MFMA16(pf, vf[t], Oacc[t]);
    }

#pragma unroll
    for (int r = 0; r < 4; ++r) {
        float l = lsum[r];
        l += __shfl_xor(l, 1, 64);
        l += __shfl_xor(l, 2, 64);
        l += __shfl_xor(l, 4, 64);
        l += __shfl_xor(l, 8, 64);
        float inv = 1.0f / l;
        int sa = qw + quad * 4 + r;
        size_t base = (((size_t)b * SS + sa) * HH + h) * 64 + l16;
        attn[base]      = (bf16_t)(Oacc[0][r] * inv);
        attn[base + 16] = (bf16_t)(Oacc[1][r] * inv);
        attn[base + 32] = (bf16_t)(Oacc[2][r] * inv);
        attn[base + 48] = (bf16_t)(Oacc[3][r] * inv);
    }
}

// ---------------------------------------------------------------------------
// Output projection, tile 128m x 64n, BK=64, 512 XCD-swizzled blocks.
__global__ __launch_bounds__(256, 4) void gemm_out_kernel(
    const bf16_t* __restrict__ A, const bf16_t* __restrict__ WoT,
    const uint16_t* __restrict__ wdet, void* __restrict__ out) {
    __shared__ __align__(16) bf16_t As[128 * 64];
    __shared__ __align__(16) bf16_t B1[64 * 64];
    const int tid = threadIdx.x, lane = tid & 63, quad = lane >> 4, l16 = lane & 15;
    const int wave = tid >> 6, wm = (wave >> 1) * 64, wn = (wave & 1) * 32;

    const int lin = blockIdx.x;
    const int xcd = lin & 7, s = lin >> 3;               // s: 0..63
    const int mb = (xcd >> 1) * 8 + (s >> 3);
    const int nb = (xcd & 1) * 8 + (s & 7);
    const int m0 = mb * 128, n0 = nb * 64;

    f32x4 acc[4][2];
#pragma unroll
    for (int i = 0; i < 4; ++i)
#pragma unroll
        for (int j = 0; j < 2; ++j) acc[i][j] = (f32x4)0.0f;

    for (int k0 = 0; k0 < DD; k0 += 64) {
        stage_128x64(A, m0, k0, As, tid);
        stage_64x64(WoT, n0, k0, B1, tid);
        __syncthreads();
#pragma unroll
        for (int half = 0; half < 2; ++half) {
            bf16x8 af[4], b1f[2];
#pragma unroll
            for (int t = 0; t < 4; ++t)
                af[t] = *(const bf16x8*)(As + (wm + t * 16 + l16) * 64 + half * 32 + quad * 8);
#pragma unroll
            for (int t = 0; t < 2; ++t)
                b1f[t] = *(const bf16x8*)(B1 + (wn + t * 16 + l16) * 64 + half * 32 + quad * 8);
#pragma unroll
            for (int i = 0; i < 4; ++i)
#pragma unroll
                for (int j = 0; j < 2; ++j)
                    acc[i][j] = MFMA16(af[i], b1f[j], acc[i][j]);
        }
        __syncthreads();
    }

    const bool f32 = detect_fp32(wdet);
#pragma unroll
    for (int i = 0; i < 4; ++i) {
        int mbase = m0 + wm + i * 16 + quad * 4;
#pragma unroll
        for (int j = 0; j < 2; ++j) {
            int n = n0 + wn + j * 16 + l16;
#pragma unroll
            for (int r = 0; r < 4; ++r) {
                size_t idx = (size_t)(mbase + r) * DD + n;
                if (f32) ((float*)out)[idx] = acc[i][j][r];
                else     ((bf16_t*)out)[idx] = (bf16_t)acc[i][j][r];
            }
        }
    }
}

// ---------------------------------------------------------------------------
extern "C" void kernel_launch(void* const* d_in, const int* in_sizes, int n_in,
                              void* d_out, int out_size, void* d_ws, size_t ws_size,
                              hipStream_t stream) {
    const void* hidden = d_in[0];
    const void* Wq = d_in[1];
    const void* Wk = d_in[2];
    const void* Wv = d_in[3];
    const void* Wo = d_in[4];
    const uint16_t* wdet = (const uint16_t*)d_in[1];
    char* ws = (char*)d_ws;

    bf16_t* roped   = (bf16_t*)(ws);                  // 8 MiB (b,s,d)
    bf16_t* hiddenb = (bf16_t*)(ws + ( 8u << 20));    // 8 MiB (fp32 path only)
    bf16_t* WqT     = (bf16_t*)(ws + (16u << 20));    // 2 MiB each, [n][k]
    bf16_t* WkT     = (bf16_t*)(ws + (18u << 20));
    bf16_t* WvT     = (bf16_t*)(ws + (20u << 20));
    bf16_t* WoT     = (bf16_t*)(ws + (22u << 20));
    bf16_t* Qb      = (bf16_t*)(ws + (24u << 20));    // 8 MiB (b,h,s,d)
    bf16_t* Kb      = (bf16_t*)(ws + (32u << 20));    // 8 MiB (b,h,s,d)
    bf16_t* Vt      = (bf16_t*)(ws + (40u << 20));    // 8 MiB (b,h,d,s)
    bf16_t* attn    = roped;  // alias: roped dead after gemm_qkv_fused

    hipLaunchKernelGGL(prep_kernel, dim3(5120), dim3(256), 0, stream,
                       hidden, Wq, Wk, Wv, Wo, roped, hiddenb,
                       WqT, WkT, WvT, WoT);
    hipLaunchKernelGGL(gemm_qkv_fused, dim3(512), dim3(256), 0, stream,
                       roped, hidden, hiddenb, wdet, WqT, WkT, WvT, Qb, Kb, Vt);
    hipLaunchKernelGGL(attn_kernel, dim3(1024), dim3(256), 0, stream,
                       Qb, Kb, Vt, attn);
    hipLaunchKernelGGL(gemm_out_kernel, dim3(512), dim3(256), 0, stream,
                       attn, WoT, wdet, d_out);
}

// Round 9
// 151.053 us; speedup vs baseline: 1.1221x; 1.1221x over previous
//
#include <hip/hip_runtime.h>
#include <hip/hip_bf16.h>
#include <cstdint>
#include <cmath>

typedef __bf16 bf16_t;
typedef __bf16 bf16x8 __attribute__((ext_vector_type(8)));
typedef __bf16 bf16x4 __attribute__((ext_vector_type(4)));
typedef float  f32x4  __attribute__((ext_vector_type(4)));

#define MFMA16(a, b, c) __builtin_amdgcn_mfma_f32_16x16x32_bf16(a, b, c, 0, 0, 0)

constexpr int   SS    = 2048;
constexpr int   DD    = 1024;
constexpr int   HH    = 16;
constexpr float SCALE = 0.125f;          // 1/sqrt(64)
constexpr float L2E   = 1.44269504088896f;

// ---------------------------------------------------------------------------
// Runtime input-dtype detector (bf16 weights vs fp32 read as uint16 halves).
__device__ __forceinline__ bool detect_fp32(const uint16_t* w) {
    uint16_t v = w[threadIdx.x & 63];
    int e = (v >> 7) & 0xFF;
    unsigned long long m = __ballot(e >= 0x80);
    return __popcll(m) >= 4;
}

__device__ __forceinline__ float ldin(const void* p, size_t i, bool f32) {
    return f32 ? ((const float*)p)[i] : (float)((const bf16_t*)p)[i];
}

// ---------------------------------------------------------------------------
// async global->LDS, 16B per lane. LDS dst must be wave-uniform base + lane*16.
__device__ __forceinline__ void gload_lds16(const bf16_t* g, bf16_t* l) {
    __builtin_amdgcn_global_load_lds(
        (const __attribute__((address_space(1))) void*)(g),
        (__attribute__((address_space(3))) void*)(l), 16, 0, 0);
}

// ---------------------------------------------------------------------------
// Merged prep: blocks [0,1024) do 8-wide vectorized RoPE+cast;
// blocks [1024,5120) transpose the four 1024x1024 weights to bf16 [n][k].
__global__ __launch_bounds__(256) void prep_kernel(
    const void* __restrict__ hidden, const void* __restrict__ Wq,
    const void* __restrict__ Wk, const void* __restrict__ Wv,
    const void* __restrict__ Wo,
    bf16_t* __restrict__ roped, bf16_t* __restrict__ hiddenb,
    bf16_t* __restrict__ WqT, bf16_t* __restrict__ WkT,
    bf16_t* __restrict__ WvT, bf16_t* __restrict__ WoT) {
    const bool f32 = detect_fp32((const uint16_t*)Wq);
    __shared__ bf16_t tile[32][33];
    if (blockIdx.x < 1024) {
        int gid = blockIdx.x * 256 + threadIdx.x;   // 2^18 threads
        int ic = (gid & 3) * 8;                     // i base within [0,32)
        int h  = (gid >> 2) & 15;
        int s  = (gid >> 6) & 2047;
        int b  = gid >> 17;
        size_t base = ((size_t)(b * SS + s)) * DD + h * 64 + ic;
        float x[8], y[8];
        if (f32) {
            const float* hp = (const float*)hidden;
            f32x4 x0 = *(const f32x4*)(hp + base);
            f32x4 x1 = *(const f32x4*)(hp + base + 4);
            f32x4 y0 = *(const f32x4*)(hp + base + 32);
            f32x4 y1 = *(const f32x4*)(hp + base + 36);
#pragma unroll
            for (int j = 0; j < 4; ++j) {
                x[j] = x0[j]; x[4 + j] = x1[j];
                y[j] = y0[j]; y[4 + j] = y1[j];
            }
        } else {
            const bf16_t* hp = (const bf16_t*)hidden;
            bf16x8 xv = *(const bf16x8*)(hp + base);
            bf16x8 yv = *(const bf16x8*)(hp + base + 32);
#pragma unroll
            for (int j = 0; j < 8; ++j) { x[j] = (float)xv[j]; y[j] = (float)yv[j]; }
        }
        bf16x8 ro, rh, hb0, hb1;
#pragma unroll
        for (int j = 0; j < 8; ++j) {
            int i = ic + j;
            float invf = exp2f(-(float)i * (13.287712379549449f / 32.0f));
            float sn, cs;
            __sincosf((float)s * invf, &sn, &cs);
            ro[j]  = (bf16_t)(x[j] * cs - y[j] * sn);
            rh[j]  = (bf16_t)(y[j] * cs + x[j] * sn);
            hb0[j] = (bf16_t)x[j];
            hb1[j] = (bf16_t)y[j];
        }
        *(bf16x8*)(roped + base)        = ro;
        *(bf16x8*)(roped + base + 32)   = rh;
        *(bf16x8*)(hiddenb + base)      = hb0;
        *(bf16x8*)(hiddenb + base + 32) = hb1;
    } else {
        int w = blockIdx.x - 1024;            // 0..4095
        int z = w >> 10;
        int yy = (w >> 5) & 31, xx = w & 31;
        const void* src = (z == 0) ? Wq : (z == 1) ? Wk : (z == 2) ? Wv : Wo;
        bf16_t*     dst = (z == 0) ? WqT : (z == 1) ? WkT : (z == 2) ? WvT : WoT;
        int tx = threadIdx.x & 31, ty = threadIdx.x >> 5;   // 32 x 8
        int x0 = xx * 32, y0 = yy * 32;
#pragma unroll
        for (int j = 0; j < 4; ++j)
            tile[ty + j * 8][tx] =
                (bf16_t)ldin(src, (size_t)(y0 + ty + j * 8) * DD + x0 + tx, f32);
        __syncthreads();
#pragma unroll
        for (int j = 0; j < 4; ++j)
            dst[(size_t)(x0 + ty + j * 8) * DD + y0 + tx] = tile[tx][ty + j * 8];
    }
}

// ---------------------------------------------------------------------------
// Staging helpers, BK=64, XOR-SWIZZLED: LDS slot (row r, chunk c) holds global
// chunk (c ^ (r&7)) of row r. Fragment readers use slot (hc ^ (row&7)) ->
// 8 distinct 4-bank groups per quarter-wave -> conflict-free (2-way = free).
__device__ __forceinline__ void stage_a128(const bf16_t* A, int m0, int k0,
                                           bf16_t* As, int tid) {
#pragma unroll
    for (int i = 0; i < 4; ++i) {
        int c = tid + i * 256;
        int r = c >> 3, g = (c & 7) ^ (r & 7);
        gload_lds16(A + (size_t)(m0 + r) * DD + k0 + g * 8, As + c * 8);
    }
}
__device__ __forceinline__ void stage_b64(const bf16_t* Bt, int n0, int k0,
                                          bf16_t* Bs, int tid) {
#pragma unroll
    for (int i = 0; i < 2; ++i) {
        int c = tid + i * 256;
        int r = c >> 3, g = (c & 7) ^ (r & 7);
        gload_lds16(Bt + (size_t)(n0 + r) * DD + k0 + g * 8, Bs + c * 8);
    }
}

// ---------------------------------------------------------------------------
// Fused QKV GEMM (round-5 structure + swizzle). Grid: 1024 blocks, XCD-slab
// swizzled. BK=64, tile 128m x 64n, 4 waves 2x2, 4 blocks/CU.
//   z=0: Q and K tiles fused (shared A=roped); z=1: V -> (b,h,d,s).
__global__ __launch_bounds__(256, 4) void gemm_qkv_fused(
    const bf16_t* __restrict__ roped, const bf16_t* __restrict__ hiddenb,
    const bf16_t* __restrict__ WqT, const bf16_t* __restrict__ WkT,
    const bf16_t* __restrict__ WvT,
    bf16_t* __restrict__ Qo, bf16_t* __restrict__ Ko, bf16_t* __restrict__ Vt) {
    __shared__ __align__(16) bf16_t As[128 * 64];
    __shared__ __align__(16) bf16_t B1[64 * 64];
    __shared__ __align__(16) bf16_t B2[64 * 64];
    const int tid = threadIdx.x, lane = tid & 63, quad = lane >> 4, l16 = lane & 15;
    const int wave = tid >> 6, wm = (wave >> 1) * 64, wn = (wave & 1) * 32;
    const int sw = l16 & 7;   // fragment-read swizzle key (row&7 == l16&7)

    const int lin = blockIdx.x;
    const int xcd = lin & 7, s = lin >> 3;
    const int z = s >> 6, rem = s & 63;
    const int mb = (xcd >> 1) * 8 + (rem >> 3);   // 0..31
    const int nb = (xcd & 1) * 8 + (rem & 7);     // 0..15
    const int m0 = mb * 128, n0 = nb * 64;

    f32x4 acc1[4][2], acc2[4][2];
#pragma unroll
    for (int i = 0; i < 4; ++i)
#pragma unroll
        for (int j = 0; j < 2; ++j) { acc1[i][j] = (f32x4)0.0f; acc2[i][j] = (f32x4)0.0f; }

    if (z == 0) {
        for (int k0 = 0; k0 < DD; k0 += 64) {
            stage_a128(roped, m0, k0, As, tid);
            stage_b64(WqT, n0, k0, B1, tid);
            stage_b64(WkT, n0, k0, B2, tid);
            __syncthreads();
#pragma unroll
            for (int half = 0; half < 2; ++half) {
                const int h4 = half * 4;
                bf16x8 af[4], b1f[2], b2f[2];
#pragma unroll
                for (int t = 0; t < 4; ++t)
                    af[t] = *(const bf16x8*)(As + (wm + t * 16 + l16) * 64 + ((h4 + quad) ^ sw) * 8);
#pragma unroll
                for (int t = 0; t < 2; ++t) {
                    b1f[t] = *(const bf16x8*)(B1 + (wn + t * 16 + l16) * 64 + ((h4 + quad) ^ sw) * 8);
                    b2f[t] = *(const bf16x8*)(B2 + (wn + t * 16 + l16) * 64 + ((h4 + quad) ^ sw) * 8);
                }
#pragma unroll
                for (int i = 0; i < 4; ++i)
#pragma unroll
                    for (int j = 0; j < 2; ++j) {
                        acc1[i][j] = MFMA16(af[i], b1f[j], acc1[i][j]);
                        acc2[i][j] = MFMA16(af[i], b2f[j], acc2[i][j]);
                    }
            }
            __syncthreads();
        }
#pragma unroll
        for (int i = 0; i < 4; ++i) {
            int mbase = m0 + wm + i * 16 + quad * 4;
            int b = mbase >> 11, sl = mbase & 2047;
#pragma unroll
            for (int j = 0; j < 2; ++j) {
                int d = wn + j * 16 + l16;
                size_t base = (((size_t)b * HH + nb) * SS + sl) * 64 + d;
#pragma unroll
                for (int r = 0; r < 4; ++r) {
                    Qo[base + 64 * r] = (bf16_t)acc1[i][j][r];
                    Ko[base + 64 * r] = (bf16_t)acc2[i][j][r];
                }
            }
        }
    } else {
        for (int k0 = 0; k0 < DD; k0 += 64) {
            stage_a128(hiddenb, m0, k0, As, tid);
            stage_b64(WvT, n0, k0, B1, tid);
            __syncthreads();
#pragma unroll
            for (int half = 0; half < 2; ++half) {
                const int h4 = half * 4;
                bf16x8 af[4], b1f[2];
#pragma unroll
                for (int t = 0; t < 4; ++t)
                    af[t] = *(const bf16x8*)(As + (wm + t * 16 + l16) * 64 + ((h4 + quad) ^ sw) * 8);
#pragma unroll
                for (int t = 0; t < 2; ++t)
                    b1f[t] = *(const bf16x8*)(B1 + (wn + t * 16 + l16) * 64 + ((h4 + quad) ^ sw) * 8);
#pragma unroll
                for (int i = 0; i < 4; ++i)
#pragma unroll
                    for (int j = 0; j < 2; ++j)
                        acc1[i][j] = MFMA16(af[i], b1f[j], acc1[i][j]);
            }
            __syncthreads();
        }
#pragma unroll
        for (int i = 0; i < 4; ++i) {
            int mbase = m0 + wm + i * 16 + quad * 4;
            int b = mbase >> 11, sl = mbase & 2047;
#pragma unroll
            for (int j = 0; j < 2; ++j) {
                int d = wn + j * 16 + l16;
                bf16x4 v;
                v[0] = (bf16_t)acc1[i][j][0]; v[1] = (bf16_t)acc1[i][j][1];
                v[2] = (bf16_t)acc1[i][j][2]; v[3] = (bf16_t)acc1[i][j][3];
                *(bf16x4*)(Vt + (((size_t)b * HH + nb) * 64 + d) * SS + sl) = v;
            }
        }
    }
}

// ---------------------------------------------------------------------------
// Banded flash attention (round-5 structure + swizzled K/V LDS staging).
// 4-wave blocks (64 queries), 32-key tiles, stage -> barrier -> compute.
__global__ __launch_bounds__(256) void attn_kernel(
    const bf16_t* __restrict__ Q, const bf16_t* __restrict__ Kk,
    const bf16_t* __restrict__ Vt, bf16_t* __restrict__ attn) {
    __shared__ __align__(16) bf16_t Ks[2][32 * 64];   // [key][d] swizzled
    __shared__ __align__(16) bf16_t Vs[2][64 * 32];   // [d][key] swizzled
    __shared__ __align__(16) bf16_t Pl[4][16 * 40];   // per-wave P, pitch 40
    const int tid = threadIdx.x, wave = tid >> 6, lane = tid & 63;
    const int quad = lane >> 4, l16 = lane & 15;
    const int sw7 = l16 & 7, sw3 = l16 & 3;

    int lin = (blockIdx.x >> 3) + 128 * (blockIdx.x & 7);   // XCD swizzle
    const int qb0 = (lin & 31) * 64;
    const int h   = (lin >> 5) & 15;
    const int b   = lin >> 9;
    const int qw  = qb0 + wave * 16;

    const size_t bh = (size_t)b * HH + h;
    const bf16_t* Qp = Q  + bh * SS * 64;
    const bf16_t* Kp = Kk + bh * SS * 64;
    const bf16_t* Vp = Vt + bh * 64 * SS;
    bf16_t* P = &Pl[wave][0];

    bf16x8 q0 = *(const bf16x8*)(Qp + (size_t)(qw + l16) * 64 + quad * 8);
    bf16x8 q1 = *(const bf16x8*)(Qp + (size_t)(qw + l16) * 64 + 32 + quad * 8);

    f32x4 Oacc[4];
#pragma unroll
    for (int t = 0; t < 4; ++t) Oacc[t] = (f32x4)0.0f;
    float lsum[4] = {0.f, 0.f, 0.f, 0.f};

    int lo = qb0 - 127; if (lo < 0) lo = 0; lo &= ~31;
    int hi = qb0 + 63 + 127; if (hi > SS - 1) hi = SS - 1;

    // swizzled staging source offsets (fixed per thread)
    const int krow = tid >> 3, kcol = ((tid & 7) ^ (krow & 7)) * 8;  // K 32x64
    const int vrow = tid >> 2, vcol = ((tid & 3) ^ (vrow & 3)) * 8;  // V^T 64x32

    int parity = 0;
    for (int kt = lo; kt <= hi; kt += 32, parity ^= 1) {
        gload_lds16(Kp + (size_t)(kt + krow) * 64 + kcol, &Ks[parity][0] + tid * 8);
        gload_lds16(Vp + (size_t)vrow * SS + kt + vcol, &Vs[parity][0] + tid * 8);
        __syncthreads();   // drains vmcnt; also fences prior-iter frag reads

        const bf16_t* Kl = &Ks[parity][0];
        const bf16_t* Vl = &Vs[parity][0];
        bf16x8 k00 = *(const bf16x8*)(Kl + l16 * 64 + (quad ^ sw7) * 8);
        bf16x8 k01 = *(const bf16x8*)(Kl + l16 * 64 + ((quad + 4) ^ sw7) * 8);
        bf16x8 k10 = *(const bf16x8*)(Kl + (16 + l16) * 64 + (quad ^ sw7) * 8);
        bf16x8 k11 = *(const bf16x8*)(Kl + (16 + l16) * 64 + ((quad + 4) ^ sw7) * 8);
        bf16x8 vf[4];
#pragma unroll
        for (int t = 0; t < 4; ++t)
            vf[t] = *(const bf16x8*)(Vl + (t * 16 + l16) * 32 + (quad ^ sw3) * 8);

        f32x4 s0 = MFMA16(q0, k00, (f32x4)0.0f);  s0 = MFMA16(q1, k01, s0);
        f32x4 s1 = MFMA16(q0, k10, (f32x4)0.0f);  s1 = MFMA16(q1, k11, s1);

        const int kr0 = kt + l16, kr1 = kt + 16 + l16;
#pragma unroll
        for (int r = 0; r < 4; ++r) {
            int qa = qw + quad * 4 + r;
            int d0 = qa - kr0; if (d0 < 0) d0 = -d0;
            int d1 = qa - kr1; if (d1 < 0) d1 = -d1;
            float p0 = (d0 < 128) ? exp2f(s0[r] * (SCALE * L2E)) : 0.0f;
            float p1 = (d1 < 128) ? exp2f(s1[r] * (SCALE * L2E)) : 0.0f;
            lsum[r] += p0 + p1;
            P[(quad * 4 + r) * 40 + l16]      = (bf16_t)p0;
            P[(quad * 4 + r) * 40 + 16 + l16] = (bf16_t)p1;
        }
        // per-wave DS ordering: write -> wait -> read (P is wave-private)
        __asm__ volatile("s_waitcnt lgkmcnt(0)" ::: "memory");
        bf16x8 pf = *(const bf16x8*)(P + l16 * 40 + quad * 8);  // A-layout P
#pragma unroll
        for (int t = 0; t < 4; ++t)
            Oacc[t] = MFMA16(pf, vf[t], Oacc[t]);
    }

#pragma unroll
    for (int r = 0; r < 4; ++r) {
        float l = lsum[r];
        l += __shfl_xor(l, 1, 64);
        l += __shfl_xor(l, 2, 64);
        l += __shfl_xor(l, 4, 64);
        l += __shfl_xor(l, 8, 64);
        float inv = 1.0f / l;
        int sa = qw + quad * 4 + r;
        size_t base = (((size_t)b * SS + sa) * HH + h) * 64 + l16;
        attn[base]      = (bf16_t)(Oacc[0][r] * inv);
        attn[base + 16] = (bf16_t)(Oacc[1][r] * inv);
        attn[base + 32] = (bf16_t)(Oacc[2][r] * inv);
        attn[base + 48] = (bf16_t)(Oacc[3][r] * inv);
    }
}

// ---------------------------------------------------------------------------
// Output projection, tile 128m x 64n, BK=64, 512 XCD-swizzled blocks.
__global__ __launch_bounds__(256, 4) void gemm_out_kernel(
    const bf16_t* __restrict__ A, const bf16_t* __restrict__ WoT,
    const uint16_t* __restrict__ wdet, void* __restrict__ out) {
    __shared__ __align__(16) bf16_t As[128 * 64];
    __shared__ __align__(16) bf16_t B1[64 * 64];
    const int tid = threadIdx.x, lane = tid & 63, quad = lane >> 4, l16 = lane & 15;
    const int wave = tid >> 6, wm = (wave >> 1) * 64, wn = (wave & 1) * 32;
    const int sw = l16 & 7;

    const int lin = blockIdx.x;
    const int xcd = lin & 7, s = lin >> 3;               // s: 0..63
    const int mb = (xcd >> 1) * 8 + (s >> 3);
    const int nb = (xcd & 1) * 8 + (s & 7);
    const int m0 = mb * 128, n0 = nb * 64;

    f32x4 acc[4][2];
#pragma unroll
    for (int i = 0; i < 4; ++i)
#pragma unroll
        for (int j = 0; j < 2; ++j) acc[i][j] = (f32x4)0.0f;

    for (int k0 = 0; k0 < DD; k0 += 64) {
        stage_a128(A, m0, k0, As, tid);
        stage_b64(WoT, n0, k0, B1, tid);
        __syncthreads();
#pragma unroll
        for (int half = 0; half < 2; ++half) {
            const int h4 = half * 4;
            bf16x8 af[4], b1f[2];
#pragma unroll
            for (int t = 0; t < 4; ++t)
                af[t] = *(const bf16x8*)(As + (wm + t * 16 + l16) * 64 + ((h4 + quad) ^ sw) * 8);
#pragma unroll
            for (int t = 0; t < 2; ++t)
                b1f[t] = *(const bf16x8*)(B1 + (wn + t * 16 + l16) * 64 + ((h4 + quad) ^ sw) * 8);
#pragma unroll
            for (int i = 0; i < 4; ++i)
#pragma unroll
                for (int j = 0; j < 2; ++j)
                    acc[i][j] = MFMA16(af[i], b1f[j], acc[i][j]);
        }
        __syncthreads();
    }

    const bool f32 = detect_fp32(wdet);
#pragma unroll
    for (int i = 0; i < 4; ++i) {
        int mbase = m0 + wm + i * 16 + quad * 4;
#pragma unroll
        for (int j = 0; j < 2; ++j) {
            int n = n0 + wn + j * 16 + l16;
#pragma unroll
            for (int r = 0; r < 4; ++r) {
                size_t idx = (size_t)(mbase + r) * DD + n;
                if (f32) ((float*)out)[idx] = acc[i][j][r];
                else     ((bf16_t*)out)[idx] = (bf16_t)acc[i][j][r];
            }
        }
    }
}

// ---------------------------------------------------------------------------
extern "C" void kernel_launch(void* const* d_in, const int* in_sizes, int n_in,
                              void* d_out, int out_size, void* d_ws, size_t ws_size,
                              hipStream_t stream) {
    const void* hidden = d_in[0];
    const void* Wq = d_in[1];
    const void* Wk = d_in[2];
    const void* Wv = d_in[3];
    const void* Wo = d_in[4];
    const uint16_t* wdet = (const uint16_t*)d_in[1];
    char* ws = (char*)d_ws;

    bf16_t* roped   = (bf16_t*)(ws);                  // 8 MiB (b,s,d)
    bf16_t* hiddenb = (bf16_t*)(ws + ( 8u << 20));    // 8 MiB (b,s,d) bf16 cast
    bf16_t* WqT     = (bf16_t*)(ws + (16u << 20));    // 2 MiB each, [n][k]
    bf16_t* WkT     = (bf16_t*)(ws + (18u << 20));
    bf16_t* WvT     = (bf16_t*)(ws + (20u << 20));
    bf16_t* WoT     = (bf16_t*)(ws + (22u << 20));
    bf16_t* Qb      = (bf16_t*)(ws + (24u << 20));    // 8 MiB (b,h,s,d)
    bf16_t* Kb      = (bf16_t*)(ws + (32u << 20));    // 8 MiB (b,h,s,d)
    bf16_t* Vt      = (bf16_t*)(ws + (40u << 20));    // 8 MiB (b,h,d,s)
    bf16_t* attn    = roped;  // alias: roped dead after gemm_qkv_fused

    hipLaunchKernelGGL(prep_kernel, dim3(5120), dim3(256), 0, stream,
                       hidden, Wq, Wk, Wv, Wo, roped, hiddenb,
                       WqT, WkT, WvT, WoT);
    hipLaunchKernelGGL(gemm_qkv_fused, dim3(1024), dim3(256), 0, stream,
                       roped, hiddenb, WqT, WkT, WvT, Qb, Kb, Vt);
    hipLaunchKernelGGL(attn_kernel, dim3(1024), dim3(256), 0, stream,
                       Qb, Kb, Vt, attn);
    hipLaunchKernelGGL(gemm_out_kernel, dim3(512), dim3(256), 0, stream,
                       attn, WoT, wdet, d_out);
}

// Round 10
// 150.833 us; speedup vs baseline: 1.1237x; 1.0015x over previous
//
#include <hip/hip_runtime.h>
#include <hip/hip_bf16.h>
#include <cstdint>
#include <cmath>

typedef __bf16 bf16_t;
typedef __bf16 bf16x8 __attribute__((ext_vector_type(8)));
typedef __bf16 bf16x4 __attribute__((ext_vector_type(4)));
typedef float  f32x4  __attribute__((ext_vector_type(4)));

#define MFMA16(a, b, c) __builtin_amdgcn_mfma_f32_16x16x32_bf16(a, b, c, 0, 0, 0)

constexpr int   SS    = 2048;
constexpr int   DD    = 1024;
constexpr int   HH    = 16;
constexpr float SCALE = 0.125f;          // 1/sqrt(64)
constexpr float L2E   = 1.44269504088896f;

// ---------------------------------------------------------------------------
// Runtime input-dtype detector (bf16 weights vs fp32 read as uint16 halves).
__device__ __forceinline__ bool detect_fp32(const uint16_t* w) {
    uint16_t v = w[threadIdx.x & 63];
    int e = (v >> 7) & 0xFF;
    unsigned long long m = __ballot(e >= 0x80);
    return __popcll(m) >= 4;
}

__device__ __forceinline__ float ldin(const void* p, size_t i, bool f32) {
    return f32 ? ((const float*)p)[i] : (float)((const bf16_t*)p)[i];
}

// ---------------------------------------------------------------------------
// async global->LDS, 16B per lane. LDS dst must be wave-uniform base + lane*16.
__device__ __forceinline__ void gload_lds16(const bf16_t* g, bf16_t* l) {
    __builtin_amdgcn_global_load_lds(
        (const __attribute__((address_space(1))) void*)(g),
        (__attribute__((address_space(3))) void*)(l), 16, 0, 0);
}

// ---------------------------------------------------------------------------
// Merged prep: blocks [0,1024) do 8-wide vectorized RoPE+cast;
// blocks [1024,5120) transpose the four 1024x1024 weights to bf16 [n][k].
// hiddenb is only materialized on the fp32 path (bf16 path reads hidden raw).
__global__ __launch_bounds__(256) void prep_kernel(
    const void* __restrict__ hidden, const void* __restrict__ Wq,
    const void* __restrict__ Wk, const void* __restrict__ Wv,
    const void* __restrict__ Wo,
    bf16_t* __restrict__ roped, bf16_t* __restrict__ hiddenb,
    bf16_t* __restrict__ WqT, bf16_t* __restrict__ WkT,
    bf16_t* __restrict__ WvT, bf16_t* __restrict__ WoT) {
    const bool f32 = detect_fp32((const uint16_t*)Wq);
    __shared__ bf16_t tile[32][33];
    if (blockIdx.x < 1024) {
        int gid = blockIdx.x * 256 + threadIdx.x;   // 2^18 threads
        int ic = (gid & 3) * 8;                     // i base within [0,32)
        int h  = (gid >> 2) & 15;
        int s  = (gid >> 6) & 2047;
        int b  = gid >> 17;
        size_t base = ((size_t)(b * SS + s)) * DD + h * 64 + ic;
        float x[8], y[8];
        if (f32) {
            const float* hp = (const float*)hidden;
            f32x4 x0 = *(const f32x4*)(hp + base);
            f32x4 x1 = *(const f32x4*)(hp + base + 4);
            f32x4 y0 = *(const f32x4*)(hp + base + 32);
            f32x4 y1 = *(const f32x4*)(hp + base + 36);
#pragma unroll
            for (int j = 0; j < 4; ++j) {
                x[j] = x0[j]; x[4 + j] = x1[j];
                y[j] = y0[j]; y[4 + j] = y1[j];
            }
        } else {
            const bf16_t* hp = (const bf16_t*)hidden;
            bf16x8 xv = *(const bf16x8*)(hp + base);
            bf16x8 yv = *(const bf16x8*)(hp + base + 32);
#pragma unroll
            for (int j = 0; j < 8; ++j) { x[j] = (float)xv[j]; y[j] = (float)yv[j]; }
        }
        bf16x8 ro, rh;
#pragma unroll
        for (int j = 0; j < 8; ++j) {
            int i = ic + j;
            float invf = exp2f(-(float)i * (13.287712379549449f / 32.0f));
            float sn, cs;
            __sincosf((float)s * invf, &sn, &cs);
            ro[j]  = (bf16_t)(x[j] * cs - y[j] * sn);
            rh[j]  = (bf16_t)(y[j] * cs + x[j] * sn);
        }
        *(bf16x8*)(roped + base)      = ro;
        *(bf16x8*)(roped + base + 32) = rh;
        if (f32) {
            bf16x8 hb0, hb1;
#pragma unroll
            for (int j = 0; j < 8; ++j) { hb0[j] = (bf16_t)x[j]; hb1[j] = (bf16_t)y[j]; }
            *(bf16x8*)(hiddenb + base)      = hb0;
            *(bf16x8*)(hiddenb + base + 32) = hb1;
        }
    } else {
        int w = blockIdx.x - 1024;            // 0..4095
        int z = w >> 10;
        int yy = (w >> 5) & 31, xx = w & 31;
        const void* src = (z == 0) ? Wq : (z == 1) ? Wk : (z == 2) ? Wv : Wo;
        bf16_t*     dst = (z == 0) ? WqT : (z == 1) ? WkT : (z == 2) ? WvT : WoT;
        int tx = threadIdx.x & 31, ty = threadIdx.x >> 5;   // 32 x 8
        int x0 = xx * 32, y0 = yy * 32;
#pragma unroll
        for (int j = 0; j < 4; ++j)
            tile[ty + j * 8][tx] =
                (bf16_t)ldin(src, (size_t)(y0 + ty + j * 8) * DD + x0 + tx, f32);
        __syncthreads();
#pragma unroll
        for (int j = 0; j < 4; ++j)
            dst[(size_t)(x0 + ty + j * 8) * DD + y0 + tx] = tile[tx][ty + j * 8];
    }
}

// ---------------------------------------------------------------------------
// Staging helpers, BK=64, XOR-SWIZZLED: LDS slot (row r, chunk c) holds global
// chunk (c ^ (r&7)) of row r. Fragment readers use slot (hc ^ (row&7)) ->
// 8 distinct 4-bank groups per quarter-wave -> conflict-free (2-way = free).
__device__ __forceinline__ void stage_a128(const bf16_t* A, int m0, int k0,
                                           bf16_t* As, int tid) {
#pragma unroll
    for (int i = 0; i < 4; ++i) {
        int c = tid + i * 256;
        int r = c >> 3, g = (c & 7) ^ (r & 7);
        gload_lds16(A + (size_t)(m0 + r) * DD + k0 + g * 8, As + c * 8);
    }
}
__device__ __forceinline__ void stage_b64(const bf16_t* Bt, int n0, int k0,
                                          bf16_t* Bs, int tid) {
#pragma unroll
    for (int i = 0; i < 2; ++i) {
        int c = tid + i * 256;
        int r = c >> 3, g = (c & 7) ^ (r & 7);
        gload_lds16(Bt + (size_t)(n0 + r) * DD + k0 + g * 8, Bs + c * 8);
    }
}

// ---------------------------------------------------------------------------
// Fused QKV GEMM. Grid: 1024 blocks. z = lin&1 INTERLEAVED so heavy fused-QK
// blocks (64 MFMA/iter) and light V blocks (32 MFMA/iter) mix on every CU
// regardless of the (undefined) workgroup->CU assignment order.
// BK=64, tile 128m x 64n, 4 waves 2x2, 4 blocks/CU, XOR-swizzled LDS.
__global__ __launch_bounds__(256, 4) void gemm_qkv_fused(
    const bf16_t* __restrict__ roped, const void* __restrict__ hidden_raw,
    const bf16_t* __restrict__ hiddenb, const uint16_t* __restrict__ wdet,
    const bf16_t* __restrict__ WqT, const bf16_t* __restrict__ WkT,
    const bf16_t* __restrict__ WvT,
    bf16_t* __restrict__ Qo, bf16_t* __restrict__ Ko, bf16_t* __restrict__ Vt) {
    __shared__ __align__(16) bf16_t As[128 * 64];
    __shared__ __align__(16) bf16_t B1[64 * 64];
    __shared__ __align__(16) bf16_t B2[64 * 64];
    const int tid = threadIdx.x, lane = tid & 63, quad = lane >> 4, l16 = lane & 15;
    const int wave = tid >> 6, wm = (wave >> 1) * 64, wn = (wave & 1) * 32;
    const int sw = l16 & 7;   // fragment-read swizzle key (row&7 == l16&7)

    const int lin = blockIdx.x;
    const int z   = lin & 1;                 // interleave heavy/light blocks
    const int p   = lin >> 1;                // 0..511 per z
    const int xcd = p & 7, rem = p >> 3;     // rem: 0..63
    const int mb  = (xcd >> 1) * 8 + (rem >> 3);   // 0..31
    const int nb  = (xcd & 1) * 8 + (rem & 7);     // 0..15
    const int m0  = mb * 128, n0 = nb * 64;

    f32x4 acc1[4][2], acc2[4][2];
#pragma unroll
    for (int i = 0; i < 4; ++i)
#pragma unroll
        for (int j = 0; j < 2; ++j) { acc1[i][j] = (f32x4)0.0f; acc2[i][j] = (f32x4)0.0f; }

    if (z == 0) {
        for (int k0 = 0; k0 < DD; k0 += 64) {
            stage_a128(roped, m0, k0, As, tid);
            stage_b64(WqT, n0, k0, B1, tid);
            stage_b64(WkT, n0, k0, B2, tid);
            __syncthreads();
#pragma unroll
            for (int half = 0; half < 2; ++half) {
                const int h4 = half * 4;
                bf16x8 af[4], b1f[2], b2f[2];
#pragma unroll
                for (int t = 0; t < 4; ++t)
                    af[t] = *(const bf16x8*)(As + (wm + t * 16 + l16) * 64 + ((h4 + quad) ^ sw) * 8);
#pragma unroll
                for (int t = 0; t < 2; ++t) {
                    b1f[t] = *(const bf16x8*)(B1 + (wn + t * 16 + l16) * 64 + ((h4 + quad) ^ sw) * 8);
                    b2f[t] = *(const bf16x8*)(B2 + (wn + t * 16 + l16) * 64 + ((h4 + quad) ^ sw) * 8);
                }
#pragma unroll
                for (int i = 0; i < 4; ++i)
#pragma unroll
                    for (int j = 0; j < 2; ++j) {
                        acc1[i][j] = MFMA16(af[i], b1f[j], acc1[i][j]);
                        acc2[i][j] = MFMA16(af[i], b2f[j], acc2[i][j]);
                    }
            }
            __syncthreads();
        }
#pragma unroll
        for (int i = 0; i < 4; ++i) {
            int mbase = m0 + wm + i * 16 + quad * 4;
            int b = mbase >> 11, sl = mbase & 2047;
#pragma unroll
            for (int j = 0; j < 2; ++j) {
                int d = wn + j * 16 + l16;
                size_t base = (((size_t)b * HH + nb) * SS + sl) * 64 + d;
#pragma unroll
                for (int r = 0; r < 4; ++r) {
                    Qo[base + 64 * r] = (bf16_t)acc1[i][j][r];
                    Ko[base + 64 * r] = (bf16_t)acc2[i][j][r];
                }
            }
        }
    } else {
        const bool f32 = detect_fp32(wdet);
        const bf16_t* A = f32 ? hiddenb : (const bf16_t*)hidden_raw;
        for (int k0 = 0; k0 < DD; k0 += 64) {
            stage_a128(A, m0, k0, As, tid);
            stage_b64(WvT, n0, k0, B1, tid);
            __syncthreads();
#pragma unroll
            for (int half = 0; half < 2; ++half) {
                const int h4 = half * 4;
                bf16x8 af[4], b1f[2];
#pragma unroll
                for (int t = 0; t < 4; ++t)
                    af[t] = *(const bf16x8*)(As + (wm + t * 16 + l16) * 64 + ((h4 + quad) ^ sw) * 8);
#pragma unroll
                for (int t = 0; t < 2; ++t)
                    b1f[t] = *(const bf16x8*)(B1 + (wn + t * 16 + l16) * 64 + ((h4 + quad) ^ sw) * 8);
#pragma unroll
                for (int i = 0; i < 4; ++i)
#pragma unroll
                    for (int j = 0; j < 2; ++j)
                        acc1[i][j] = MFMA16(af[i], b1f[j], acc1[i][j]);
            }
            __syncthreads();
        }
#pragma unroll
        for (int i = 0; i < 4; ++i) {
            int mbase = m0 + wm + i * 16 + quad * 4;
            int b = mbase >> 11, sl = mbase & 2047;
#pragma unroll
            for (int j = 0; j < 2; ++j) {
                int d = wn + j * 16 + l16;
                bf16x4 v;
                v[0] = (bf16_t)acc1[i][j][0]; v[1] = (bf16_t)acc1[i][j][1];
                v[2] = (bf16_t)acc1[i][j][2]; v[3] = (bf16_t)acc1[i][j][3];
                *(bf16x4*)(Vt + (((size_t)b * HH + nb) * 64 + d) * SS + sl) = v;
            }
        }
    }
}

// ---------------------------------------------------------------------------
// Banded flash attention (round-9: 4-wave blocks, 32-key tiles, swizzled LDS).
__global__ __launch_bounds__(256) void attn_kernel(
    const bf16_t* __restrict__ Q, const bf16_t* __restrict__ Kk,
    const bf16_t* __restrict__ Vt, bf16_t* __restrict__ attn) {
    __shared__ __align__(16) bf16_t Ks[2][32 * 64];   // [key][d] swizzled
    __shared__ __align__(16) bf16_t Vs[2][64 * 32];   // [d][key] swizzled
    __shared__ __align__(16) bf16_t Pl[4][16 * 40];   // per-wave P, pitch 40
    const int tid = threadIdx.x, wave = tid >> 6, lane = tid & 63;
    const int quad = lane >> 4, l16 = lane & 15;
    const int sw7 = l16 & 7, sw3 = l16 & 3;

    int lin = (blockIdx.x >> 3) + 128 * (blockIdx.x & 7);   // XCD swizzle
    const int qb0 = (lin & 31) * 64;
    const int h   = (lin >> 5) & 15;
    const int b   = lin >> 9;
    const int qw  = qb0 + wave * 16;

    const size_t bh = (size_t)b * HH + h;
    const bf16_t* Qp = Q  + bh * SS * 64;
    const bf16_t* Kp = Kk + bh * SS * 64;
    const bf16_t* Vp = Vt + bh * 64 * SS;
    bf16_t* P = &Pl[wave][0];

    bf16x8 q0 = *(const bf16x8*)(Qp + (size_t)(qw + l16) * 64 + quad * 8);
    bf16x8 q1 = *(const bf16x8*)(Qp + (size_t)(qw + l16) * 64 + 32 + quad * 8);

    f32x4 Oacc[4];
#pragma unroll
    for (int t = 0; t < 4; ++t) Oacc[t] = (f32x4)0.0f;
    float lsum[4] = {0.f, 0.f, 0.f, 0.f};

    int lo = qb0 - 127; if (lo < 0) lo = 0; lo &= ~31;
    int hi = qb0 + 63 + 127; if (hi > SS - 1) hi = SS - 1;

    const int krow = tid >> 3, kcol = ((tid & 7) ^ (krow & 7)) * 8;  // K 32x64
    const int vrow = tid >> 2, vcol = ((tid & 3) ^ (vrow & 3)) * 8;  // V^T 64x32

    int parity = 0;
    for (int kt = lo; kt <= hi; kt += 32, parity ^= 1) {
        gload_lds16(Kp + (size_t)(kt + krow) * 64 + kcol, &Ks[parity][0] + tid * 8);
        gload_lds16(Vp + (size_t)vrow * SS + kt + vcol, &Vs[parity][0] + tid * 8);
        __syncthreads();   // drains vmcnt; also fences prior-iter frag reads

        const bf16_t* Kl = &Ks[parity][0];
        const bf16_t* Vl = &Vs[parity][0];
        bf16x8 k00 = *(const bf16x8*)(Kl + l16 * 64 + (quad ^ sw7) * 8);
        bf16x8 k01 = *(const bf16x8*)(Kl + l16 * 64 + ((quad + 4) ^ sw7) * 8);
        bf16x8 k10 = *(const bf16x8*)(Kl + (16 + l16) * 64 + (quad ^ sw7) * 8);
        bf16x8 k11 = *(const bf16x8*)(Kl + (16 + l16) * 64 + ((quad + 4) ^ sw7) * 8);
        bf16x8 vf[4];
#pragma unroll
        for (int t = 0; t < 4; ++t)
            vf[t] = *(const bf16x8*)(Vl + (t * 16 + l16) * 32 + (quad ^ sw3) * 8);

        f32x4 s0 = MFMA16(q0, k00, (f32x4)0.0f);  s0 = MFMA16(q1, k01, s0);
        f32x4 s1 = MFMA16(q0, k10, (f32x4)0.0f);  s1 = MFMA16(q1, k11, s1);

        const int kr0 = kt + l16, kr1 = kt + 16 + l16;
#pragma unroll
        for (int r = 0; r < 4; ++r) {
            int qa = qw + quad * 4 + r;
            int d0 = qa - kr0; if (d0 < 0) d0 = -d0;
            int d1 = qa - kr1; if (d1 < 0) d1 = -d1;
            float p0 = (d0 < 128) ? exp2f(s0[r] * (SCALE * L2E)) : 0.0f;
            float p1 = (d1 < 128) ? exp2f(s1[r] * (SCALE * L2E)) : 0.0f;
            lsum[r] += p0 + p1;
            P[(quad * 4 + r) * 40 + l16]      = (bf16_t)p0;
            P[(quad * 4 + r) * 40 + 16 + l16] = (bf16_t)p1;
        }
        // per-wave DS ordering: write -> wait -> read (P is wave-private)
        __asm__ volatile("s_waitcnt lgkmcnt(0)" ::: "memory");
        bf16x8 pf = *(const bf16x8*)(P + l16 * 40 + quad * 8);  // A-layout P
#pragma unroll
        for (int t = 0; t < 4; ++t)
            Oacc[t] = MFMA16(pf, vf[t], Oacc[t]);
    }

#pragma unroll
    for (int r = 0; r < 4; ++r) {
        float l = lsum[r];
        l += __shfl_xor(l, 1, 64);
        l += __shfl_xor(l, 2, 64);
        l += __shfl_xor(l, 4, 64);
        l += __shfl_xor(l, 8, 64);
        float inv = 1.0f / l;
        int sa = qw + quad * 4 + r;
        size_t base = (((size_t)b * SS + sa) * HH + h) * 64 + l16;
        attn[base]      = (bf16_t)(Oacc[0][r] * inv);
        attn[base + 16] = (bf16_t)(Oacc[1][r] * inv);
        attn[base + 32] = (bf16_t)(Oacc[2][r] * inv);
        attn[base + 48] = (bf16_t)(Oacc[3][r] * inv);
    }
}

// ---------------------------------------------------------------------------
// Output projection, tile 128m x 64n, BK=64, 512 XCD-swizzled blocks.
__global__ __launch_bounds__(256, 4) void gemm_out_kernel(
    const bf16_t* __restrict__ A, const bf16_t* __restrict__ WoT,
    const uint16_t* __restrict__ wdet, void* __restrict__ out) {
    __shared__ __align__(16) bf16_t As[128 * 64];
    __shared__ __align__(16) bf16_t B1[64 * 64];
    const int tid = threadIdx.x, lane = tid & 63, quad = lane >> 4, l16 = lane & 15;
    const int wave = tid >> 6, wm = (wave >> 1) * 64, wn = (wave & 1) * 32;
    const int sw = l16 & 7;

    const int lin = blockIdx.x;
    const int xcd = lin & 7, s = lin >> 3;               // s: 0..63
    const int mb = (xcd >> 1) * 8 + (s >> 3);
    const int nb = (xcd & 1) * 8 + (s & 7);
    const int m0 = mb * 128, n0 = nb * 64;

    f32x4 acc[4][2];
#pragma unroll
    for (int i = 0; i < 4; ++i)
#pragma unroll
        for (int j = 0; j < 2; ++j) acc[i][j] = (f32x4)0.0f;

    for (int k0 = 0; k0 < DD; k0 += 64) {
        stage_a128(A, m0, k0, As, tid);
        stage_b64(WoT, n0, k0, B1, tid);
        __syncthreads();
#pragma unroll
        for (int half = 0; half < 2; ++half) {
            const int h4 = half * 4;
            bf16x8 af[4], b1f[2];
#pragma unroll
            for (int t = 0; t < 4; ++t)
                af[t] = *(const bf16x8*)(As + (wm + t * 16 + l16) * 64 + ((h4 + quad) ^ sw) * 8);
#pragma unroll
            for (int t = 0; t < 2; ++t)
                b1f[t] = *(const bf16x8*)(B1 + (wn + t * 16 + l16) * 64 + ((h4 + quad) ^ sw) * 8);
#pragma unroll
            for (int i = 0; i < 4; ++i)
#pragma unroll
                for (int j = 0; j < 2; ++j)
                    acc[i][j] = MFMA16(af[i], b1f[j], acc[i][j]);
        }
        __syncthreads();
    }

    const bool f32 = detect_fp32(wdet);
#pragma unroll
    for (int i = 0; i < 4; ++i) {
        int mbase = m0 + wm + i * 16 + quad * 4;
#pragma unroll
        for (int j = 0; j < 2; ++j) {
            int n = n0 + wn + j * 16 + l16;
#pragma unroll
            for (int r = 0; r < 4; ++r) {
                size_t idx = (size_t)(mbase + r) * DD + n;
                if (f32) ((float*)out)[idx] = acc[i][j][r];
                else     ((bf16_t*)out)[idx] = (bf16_t)acc[i][j][r];
            }
        }
    }
}

// ---------------------------------------------------------------------------
extern "C" void kernel_launch(void* const* d_in, const int* in_sizes, int n_in,
                              void* d_out, int out_size, void* d_ws, size_t ws_size,
                              hipStream_t stream) {
    const void* hidden = d_in[0];
    const void* Wq = d_in[1];
    const void* Wk = d_in[2];
    const void* Wv = d_in[3];
    const void* Wo = d_in[4];
    const uint16_t* wdet = (const uint16_t*)d_in[1];
    char* ws = (char*)d_ws;

    bf16_t* roped   = (bf16_t*)(ws);                  // 8 MiB (b,s,d)
    bf16_t* hiddenb = (bf16_t*)(ws + ( 8u << 20));    // 8 MiB (fp32 path only)
    bf16_t* WqT     = (bf16_t*)(ws + (16u << 20));    // 2 MiB each, [n][k]
    bf16_t* WkT     = (bf16_t*)(ws + (18u << 20));
    bf16_t* WvT     = (bf16_t*)(ws + (20u << 20));
    bf16_t* WoT     = (bf16_t*)(ws + (22u << 20));
    bf16_t* Qb      = (bf16_t*)(ws + (24u << 20));    // 8 MiB (b,h,s,d)
    bf16_t* Kb      = (bf16_t*)(ws + (32u << 20));    // 8 MiB (b,h,s,d)
    bf16_t* Vt      = (bf16_t*)(ws + (40u << 20));    // 8 MiB (b,h,d,s)
    bf16_t* attn    = roped;  // alias: roped dead after gemm_qkv_fused

    hipLaunchKernelGGL(prep_kernel, dim3(5120), dim3(256), 0, stream,
                       hidden, Wq, Wk, Wv, Wo, roped, hiddenb,
                       WqT, WkT, WvT, WoT);
    hipLaunchKernelGGL(gemm_qkv_fused, dim3(1024), dim3(256), 0, stream,
                       roped, hidden, hiddenb, wdet, WqT, WkT, WvT, Qb, Kb, Vt);
    hipLaunchKernelGGL(attn_kernel, dim3(1024), dim3(256), 0, stream,
                       Qb, Kb, Vt, attn);
    hipLaunchKernelGGL(gemm_out_kernel, dim3(512), dim3(256), 0, stream,
                       attn, WoT, wdet, d_out);
}